// Round 8
// baseline (474.860 us; speedup 1.0000x reference)
//
#include <hip/hip_runtime.h>

// CompetitiveLayer: K = param^2 (4096x4096 f32), 21 iterations of
//   AF = AT/(1+K@BF); BF = BT/(1+AF@K), then C = K*AF[:,None]*BF[None,:].
//
// Ladder: 1645 (R0) -> 325 (R6 fence-free relaxed sync) -> 309 (R7 group
// flags) -> 380 (R8 regression) -> 220 steady / 303 harness (R9: self-
// validating sign-parity exchange, no flags/drains/zeroing).
//
// R10: attack poll-storm + fan-in line locality.
//   - Transposed partials ypart[slot][j][g]: one element's 16 partials in
//     ONE 64B line. Consumer polls via 4x global_load_dwordx4 sc0 sc1
//     (inline asm, single vmcnt(0)) instead of 16 scalar agent loads.
//   - s_sleep(1) backoff on failed poll rounds only: caps the ~160 GT/s
//     L3-bypass request storm 65K spinning threads generate.
//   - kl chunk-interleaved lane-private layout [ck][w][l]: each read is 64
//     consecutive 16B chunks -> provably conflict-free (diagnostic: if
//     SQ_LDS_BANK_CONFLICT stays ~2e7, conflicts are bpermute-inherent and
//     time-free per m136; R8's null counter delta already hinted kl was
//     never the counted source).
//   - Everything else identical to R9 (proven): sign-parity validation
//     (poison 0xAA=-3.03e-13 and 0 rejected both parities), period-3 slots
//     (odd -> stale slot always opposite sign), LDS-only barriers,
//     butterfly reductions, 16-way cndmask select, waves_per_eu(1,1).

constexpr int N     = 4096;
constexpr int NITER = 21;
constexpr int NBLK  = 256;
constexpr int RREG  = 7;           // subtile rows 0..RREG-1 in VGPRs
constexpr int RLDS  = 16 - RREG;   // subtile rows RREG..15 in LDS (lane-private)

typedef float f32x4 __attribute__((ext_vector_type(4)));

__device__ __forceinline__ float ld_agent(const float* p) {
    return __hip_atomic_load(p, __ATOMIC_RELAXED, __HIP_MEMORY_SCOPE_AGENT);
}
__device__ __forceinline__ void st_agent(float* p, float v) {
    __hip_atomic_store(p, v, __ATOMIC_RELAXED, __HIP_MEMORY_SCOPE_AGENT);
}
// LDS-only block barrier: no vmcnt drain (no store-ack stall).
__device__ __forceinline__ void sync_lds() {
    asm volatile("s_waitcnt lgkmcnt(0)" ::: "memory");
    __builtin_amdgcn_s_barrier();
    asm volatile("" ::: "memory");
}

// Poll one 64B line (16 partials), sign-validated; return decoded sum.
// 4x dwordx4 with sc0 sc1 (agent-coherent bypass), one vmcnt(0)/round.
__device__ __forceinline__ float poll_line16(const float* p, float sgn) {
    for (;;) {
        f32x4 a, b, c, d;
        asm volatile(
            "global_load_dwordx4 %0, %4, off sc0 sc1\n\t"
            "global_load_dwordx4 %1, %4, off offset:16 sc0 sc1\n\t"
            "global_load_dwordx4 %2, %4, off offset:32 sc0 sc1\n\t"
            "global_load_dwordx4 %3, %4, off offset:48 sc0 sc1\n\t"
            "s_waitcnt vmcnt(0)"
            : "=&v"(a), "=&v"(b), "=&v"(c), "=&v"(d)
            : "v"(p)
            : "memory");
        bool ok = true;
        #pragma unroll
        for (int i = 0; i < 4; ++i) {
            ok &= (a[i] * sgn > 1e-9f);
            ok &= (b[i] * sgn > 1e-9f);
            ok &= (c[i] * sgn > 1e-9f);
            ok &= (d[i] * sgn > 1e-9f);
        }
        if (ok) {
            float s = ((a[0] + a[1]) + (a[2] + a[3]))
                    + ((b[0] + b[1]) + (b[2] + b[3]))
                    + ((c[0] + c[1]) + (c[2] + c[3]))
                    + ((d[0] + d[1]) + (d[2] + d[3]));
            return s * sgn;
        }
        __builtin_amdgcn_s_sleep(1);   // backoff: cap the poll storm
    }
}

// Block (bR,bC) owns the 256x256 tile of K. Lane (rl,cl) owns a 16x16 sub-tile.
__global__ void
__attribute__((amdgpu_flat_work_group_size(256, 256)))
__attribute__((amdgpu_waves_per_eu(1, 1)))
competitive_persistent(const float* __restrict__ AT, const float* __restrict__ BT,
                       const float* __restrict__ P,  float* __restrict__ C,
                       float* __restrict__ ws)
{
    const int b  = blockIdx.x;       // 0..255
    const int t  = threadIdx.x;      // 0..255
    const int bR = b >> 4, bC = b & 15;
    const int R0 = bR << 8, C0 = bC << 8;
    const int rl = t >> 4, cl = t & 15;
    const int row0 = R0 + rl * 16;
    const int col0 = C0 + cl * 16;
    const int w    = t >> 6;         // wave id 0..3
    const int l    = t & 63;         // lane id

    // ws layout (host-zeroed; 0 and 0xAA poison invalid for both parities):
    //   yrp[3][4096][16]  row partials: elem i's 16 col-slices = one 64B line
    //   ycp[3][4096][16]  col partials: elem j's 16 row-slices = one 64B line
    float* yrp = ws;
    float* ycp = ws + 3 * (size_t)N * 16;

    __shared__ __align__(16) float xsh[256];    // BF slice
    __shared__ __align__(16) float xsh2[256];   // AF slice
    __shared__ __align__(16) float red[1024];
    // Lane-private K spillover, chunk-interleaved: chunk ck=(r-RREG)*4+q of
    // lane (w,l) at kl4[(ck*4+w)*64 + l]. Reads/writes are 64 consecutive
    // 16B chunks per instruction -> conflict-free by construction. 144 KiB.
    __shared__ __align__(16) f32x4 kl4[RLDS * 4 * 4 * 64];

    // ---- Load K = param^2: 7 rows/lane in registers, 9 rows/lane in LDS ----
    float k[RREG * 16];
    #pragma unroll
    for (int r = 0; r < 16; ++r) {
        const float4* src = (const float4*)(P + (size_t)(row0 + r) * N + col0);
        #pragma unroll
        for (int q = 0; q < 4; ++q) {
            float4 v = src[q];
            if (r < RREG) {
                k[r * 16 + q * 4 + 0] = v.x * v.x;
                k[r * 16 + q * 4 + 1] = v.y * v.y;
                k[r * 16 + q * 4 + 2] = v.z * v.z;
                k[r * 16 + q * 4 + 3] = v.w * v.w;
            } else {
                f32x4 s;
                s[0] = v.x * v.x; s[1] = v.y * v.y;
                s[2] = v.z * v.z; s[3] = v.w * v.w;
                kl4[(((r - RREG) * 4 + q) * 4 + w) * 64 + l] = s;
            }
        }
    }
    sync_lds();

    #pragma unroll 1
    for (int it = 0; it < NITER; ++it) {
        const int   sC      = it % 3;
        const float sgn_cur = (it & 1) ? -1.0f : 1.0f;

        // ---- BF stage: BF = BT/(1+sum_g ycp[sP][C0+t][g]) ----
        if (it > 0) {
            const int sP = (it + 2) % 3;            // slot of iteration it-1
            const float sum =
                poll_line16(ycp + ((size_t)sP * N + C0 + t) * 16, -sgn_cur);
            xsh[t] = BT[C0 + t] / (1.0f + sum);
        } else {
            xsh[t] = BT[C0 + t];                    // y_col == 0 at it=0
        }
        sync_lds();

        // ---- rowPhase: y_row partial for this tile ----
        {
            float xv[16];
            const float4* xs4 = (const float4*)(xsh + cl * 16);
            #pragma unroll
            for (int q = 0; q < 4; ++q) {
                float4 v = xs4[q];
                xv[q * 4 + 0] = v.x; xv[q * 4 + 1] = v.y;
                xv[q * 4 + 2] = v.z; xv[q * 4 + 3] = v.w;
            }
            float part[16];
            #pragma unroll
            for (int r = 0; r < 16; ++r) part[r] = 0.0f;
            #pragma unroll
            for (int c = 0; c < 16; ++c) {
                const float x = xv[c];
                #pragma unroll
                for (int r = 0; r < RREG; ++r)
                    part[r] = fmaf(k[r * 16 + c], x, part[r]);
            }
            #pragma unroll
            for (int r = RREG; r < 16; ++r) {
                #pragma unroll
                for (int q = 0; q < 4; ++q) {
                    f32x4 kv = kl4[(((r - RREG) * 4 + q) * 4 + w) * 64 + l];
                    part[r] = fmaf(kv[0], xv[q * 4 + 0], part[r]);
                    part[r] = fmaf(kv[1], xv[q * 4 + 1], part[r]);
                    part[r] = fmaf(kv[2], xv[q * 4 + 2], part[r]);
                    part[r] = fmaf(kv[3], xv[q * 4 + 3], part[r]);
                }
            }
            // Full butterfly over cl-bits: every lane ends with all 16 totals.
            #pragma unroll
            for (int off = 1; off < 16; off <<= 1) {
                #pragma unroll
                for (int r = 0; r < 16; ++r)
                    part[r] += __shfl_xor(part[r], off, 64);
            }
            // Lane (rl,cl) stores row R0+t into line (R0+t), slot g=bC.
            float myv = part[0];
            #pragma unroll
            for (int r = 1; r < 16; ++r) myv = (cl == r) ? part[r] : myv;
            st_agent(yrp + ((size_t)sC * N + R0 + t) * 16 + bC, sgn_cur * myv);
        }

        // ---- AF stage: AF = AT/(1+sum_g yrp[sC][R0+t][g]) ----
        {
            const float sum =
                poll_line16(yrp + ((size_t)sC * N + R0 + t) * 16, sgn_cur);
            xsh2[t] = AT[R0 + t] / (1.0f + sum);
        }
        sync_lds();

        // ---- colPhase: y_col partial for this tile ----
        {
            float av[16];
            #pragma unroll
            for (int r = 0; r < 16; ++r) av[r] = xsh2[rl * 16 + r];
            float part[16];
            #pragma unroll
            for (int c = 0; c < 16; ++c) part[c] = 0.0f;
            #pragma unroll
            for (int r = 0; r < RREG; ++r) {
                const float a = av[r];
                #pragma unroll
                for (int c = 0; c < 16; ++c)
                    part[c] = fmaf(k[r * 16 + c], a, part[c]);
            }
            #pragma unroll
            for (int r = RREG; r < 16; ++r) {
                const float a = av[r];
                #pragma unroll
                for (int q = 0; q < 4; ++q) {
                    f32x4 kv = kl4[(((r - RREG) * 4 + q) * 4 + w) * 64 + l];
                    part[q * 4 + 0] = fmaf(kv[0], a, part[q * 4 + 0]);
                    part[q * 4 + 1] = fmaf(kv[1], a, part[q * 4 + 1]);
                    part[q * 4 + 2] = fmaf(kv[2], a, part[q * 4 + 2]);
                    part[q * 4 + 3] = fmaf(kv[3], a, part[q * 4 + 3]);
                }
            }
            #pragma unroll
            for (int c = 0; c < 16; ++c) {
                part[c] += __shfl_xor(part[c], 16, 64);
                part[c] += __shfl_xor(part[c], 32, 64);
            }
            if ((t & 63) < 16) {          // one lane per cl per wave
                #pragma unroll
                for (int c = 0; c < 16; ++c)
                    red[w * 256 + cl * 16 + c] = part[c];
            }
            sync_lds();
            const float s4 = red[t] + red[256 + t] + red[512 + t] + red[768 + t];
            st_agent(ycp + ((size_t)sC * N + C0 + t) * 16 + bR, sgn_cur * s4);
        }
    }

    // ---- Epilogue: C = K * AF[:,None] * BF[None,:] ----
    // AF(20) still in xsh2. BF_final from y_col(20): slot 20%3=2, sign +.
    sync_lds();   // all waves past their red reads before red is reused
    {
        const float sum = poll_line16(ycp + ((size_t)2 * N + C0 + t) * 16, 1.0f);
        red[t] = BT[C0 + t] / (1.0f + sum);
    }
    sync_lds();

    float af[16], bf[16];
    #pragma unroll
    for (int r = 0; r < 16; ++r) af[r] = xsh2[rl * 16 + r];
    #pragma unroll
    for (int c = 0; c < 16; ++c) bf[c] = red[cl * 16 + c];

    #pragma unroll
    for (int r = 0; r < 16; ++r) {
        float4* dst = (float4*)(C + (size_t)(row0 + r) * N + col0);
        const float a = af[r];
        #pragma unroll
        for (int q = 0; q < 4; ++q) {
            f32x4 kv;
            if (r < RREG) {
                kv[0] = k[r * 16 + q * 4 + 0];
                kv[1] = k[r * 16 + q * 4 + 1];
                kv[2] = k[r * 16 + q * 4 + 2];
                kv[3] = k[r * 16 + q * 4 + 3];
            } else {
                kv = kl4[(((r - RREG) * 4 + q) * 4 + w) * 64 + l];
            }
            float4 o;
            o.x = kv[0] * a * bf[q * 4 + 0];
            o.y = kv[1] * a * bf[q * 4 + 1];
            o.z = kv[2] * a * bf[q * 4 + 2];
            o.w = kv[3] * a * bf[q * 4 + 3];
            dst[q] = o;
        }
    }
}

extern "C" void kernel_launch(void* const* d_in, const int* in_sizes, int n_in,
                              void* d_out, int out_size, void* d_ws, size_t ws_size,
                              hipStream_t stream) {
    const float* AT = (const float*)d_in[0];
    const float* BT = (const float*)d_in[1];
    const float* P  = (const float*)d_in[2];
    float*       C  = (float*)d_out;
    float*       ws = (float*)d_ws;

    // Zero the 2 x 3 x 4096 x 16 partial region (1.5 MiB). Zero (like the
    // 0xAA poison = -3.03e-13) is magnitude-invalid for both parities, so
    // any pre-state is safe even without the harness re-poison.
    hipMemsetAsync(d_ws, 0, 2 * 3 * (size_t)N * 16 * sizeof(float), stream);

    competitive_persistent<<<dim3(NBLK), dim3(256), 0, stream>>>(AT, BT, P, C, ws);
}

// Round 9
// 273.437 us; speedup vs baseline: 1.7366x; 1.7366x over previous
//
#include <hip/hip_runtime.h>

// CompetitiveLayer: K = param^2 (4096x4096 f32), 21 iterations of
//   AF = AT/(1+K@BF); BF = BT/(1+AF@K), then C = K*AF[:,None]*BF[None,:].
//
// Ladder: 1645 (R0) -> 325 (R6 fence-free relaxed sync) -> 309 (R7 group
// flags) -> 380 (R8 regr) -> 220 steady/303 harness (R9 sign-parity
// self-validating exchange) -> 388 (R10 regr: transposed [elem][g] layout
// made producer stores 4B-stride-64B -> 16x write amplification,
// WRITE 76->151GB FETCH 60->133GB; ALSO proved kl was the bank-conflict
// source: 2.15e7 -> 1.6e6 with chunk-interleaved kl4 -- but never a time
// factor).
//
// R11 = R9 structure (proven best) + the two clean survivors of R10:
//   - kl4 chunk-interleaved lane-private K spillover (conflict-free, free)
//   - s_sleep(1) backoff on FAILED poll rounds only: clean test of the
//     poll-storm theory (R10's test was confounded by the store layout)
//   - AT/BT loop-invariant loads hoisted to registers
// Everything else byte-identical to R9: sign-parity validation (0xAA poison
// = -3.03e-13 and 0 invalid both parities), period-3 slots, LDS-only
// barriers, butterfly reductions, coalesced slice stores, waves_per_eu(1,1).

constexpr int N     = 4096;
constexpr int NITER = 21;
constexpr int NBLK  = 256;
constexpr int RREG  = 7;           // subtile rows 0..RREG-1 in VGPRs
constexpr int RLDS  = 16 - RREG;   // subtile rows RREG..15 in LDS (lane-private)

typedef float f32x4 __attribute__((ext_vector_type(4)));

__device__ __forceinline__ float ld_agent(const float* p) {
    return __hip_atomic_load(p, __ATOMIC_RELAXED, __HIP_MEMORY_SCOPE_AGENT);
}
__device__ __forceinline__ void st_agent(float* p, float v) {
    __hip_atomic_store(p, v, __ATOMIC_RELAXED, __HIP_MEMORY_SCOPE_AGENT);
}
// LDS-only block barrier: no vmcnt drain (no store-ack stall).
__device__ __forceinline__ void sync_lds() {
    asm volatile("s_waitcnt lgkmcnt(0)" ::: "memory");
    __builtin_amdgcn_s_barrier();
    asm volatile("" ::: "memory");
}

// Poll 16 slice values at stride N, sign-validated; return decoded sum.
// Backoff only on failed rounds (first round is free).
__device__ __forceinline__ float poll_sum16(const float* p, float sgn) {
    float v[16];
    #pragma unroll
    for (int g = 0; g < 16; ++g) v[g] = ld_agent(p + (size_t)g * N);
    for (;;) {
        bool ok = true;
        #pragma unroll
        for (int g = 0; g < 16; ++g) ok &= (v[g] * sgn > 1e-9f);
        if (ok) break;
        __builtin_amdgcn_s_sleep(1);     // cap the poll storm (~27ns)
        #pragma unroll
        for (int g = 0; g < 16; ++g) {
            if (!(v[g] * sgn > 1e-9f)) v[g] = ld_agent(p + (size_t)g * N);
        }
    }
    float s = 0.0f;
    #pragma unroll
    for (int g = 0; g < 16; ++g) s += v[g];
    return s * sgn;   // == sum of |v[g]|
}

// Block (bR,bC) owns the 256x256 tile of K. Lane (rl,cl) owns a 16x16 sub-tile.
__global__ void
__attribute__((amdgpu_flat_work_group_size(256, 256)))
__attribute__((amdgpu_waves_per_eu(1, 1)))
competitive_persistent(const float* __restrict__ AT, const float* __restrict__ BT,
                       const float* __restrict__ P,  float* __restrict__ C,
                       float* __restrict__ ws)
{
    const int b  = blockIdx.x;       // 0..255
    const int t  = threadIdx.x;      // 0..255
    const int bR = b >> 4, bC = b & 15;
    const int R0 = bR << 8, C0 = bC << 8;
    const int rl = t >> 4, cl = t & 15;
    const int row0 = R0 + rl * 16;
    const int col0 = C0 + cl * 16;
    const int w    = t >> 6;         // wave id 0..3
    const int l    = t & 63;         // lane id

    // ws layout (host-zeroed; 0 and 0xAA poison invalid for both parities):
    //   yrp[3][16][4096]  row-phase partials (slot, slice bC, rows)
    //   ycp[3][16][4096]  col-phase partials (slot, slice bR, cols)
    float* yrp = ws;
    float* ycp = ws + 3 * 16 * (size_t)N;

    __shared__ __align__(16) float xsh[256];    // BF slice
    __shared__ __align__(16) float xsh2[256];   // AF slice
    __shared__ __align__(16) float red[1024];
    // Lane-private K spillover, chunk-interleaved: chunk ck=(r-RREG)*4+q of
    // lane (w,l) at kl4[(ck*4+w)*64 + l]. Each access: 64 consecutive 16B
    // chunks per wave -> conflict-free (R10-verified: 2.15e7 -> 1.6e6).
    __shared__ __align__(16) f32x4 kl4[RLDS * 4 * 4 * 64];  // 144 KiB

    // Loop-invariant target-vector elements (hoisted: 2 global loads total).
    const float bt_val = BT[C0 + t];
    const float at_val = AT[R0 + t];

    // ---- Load K = param^2: 7 rows/lane in registers, 9 rows/lane in LDS ----
    float k[RREG * 16];
    #pragma unroll
    for (int r = 0; r < 16; ++r) {
        const float4* src = (const float4*)(P + (size_t)(row0 + r) * N + col0);
        #pragma unroll
        for (int q = 0; q < 4; ++q) {
            float4 v = src[q];
            if (r < RREG) {
                k[r * 16 + q * 4 + 0] = v.x * v.x;
                k[r * 16 + q * 4 + 1] = v.y * v.y;
                k[r * 16 + q * 4 + 2] = v.z * v.z;
                k[r * 16 + q * 4 + 3] = v.w * v.w;
            } else {
                f32x4 s;
                s[0] = v.x * v.x; s[1] = v.y * v.y;
                s[2] = v.z * v.z; s[3] = v.w * v.w;
                kl4[(((r - RREG) * 4 + q) * 4 + w) * 64 + l] = s;
            }
        }
    }
    sync_lds();

    #pragma unroll 1
    for (int it = 0; it < NITER; ++it) {
        const int   sC      = it % 3;
        const float sgn_cur = (it & 1) ? -1.0f : 1.0f;

        // ---- BF stage: BF = BT/(1+sum_r ycp[sP][r][C0+t]) ----
        if (it > 0) {
            const int sP = (it + 2) % 3;            // slot of iteration it-1
            const float sum = poll_sum16(ycp + (size_t)sP * 16 * N + C0 + t, -sgn_cur);
            xsh[t] = bt_val / (1.0f + sum);
        } else {
            xsh[t] = bt_val;                        // y_col == 0 at it=0
        }
        sync_lds();

        // ---- rowPhase: y_row partial for this tile ----
        {
            float xv[16];
            const float4* xs4 = (const float4*)(xsh + cl * 16);
            #pragma unroll
            for (int q = 0; q < 4; ++q) {
                float4 v = xs4[q];
                xv[q * 4 + 0] = v.x; xv[q * 4 + 1] = v.y;
                xv[q * 4 + 2] = v.z; xv[q * 4 + 3] = v.w;
            }
            float part[16];
            #pragma unroll
            for (int r = 0; r < 16; ++r) part[r] = 0.0f;
            #pragma unroll
            for (int c = 0; c < 16; ++c) {
                const float x = xv[c];
                #pragma unroll
                for (int r = 0; r < RREG; ++r)
                    part[r] = fmaf(k[r * 16 + c], x, part[r]);
            }
            #pragma unroll
            for (int r = RREG; r < 16; ++r) {
                #pragma unroll
                for (int q = 0; q < 4; ++q) {
                    f32x4 kv = kl4[(((r - RREG) * 4 + q) * 4 + w) * 64 + l];
                    part[r] = fmaf(kv[0], xv[q * 4 + 0], part[r]);
                    part[r] = fmaf(kv[1], xv[q * 4 + 1], part[r]);
                    part[r] = fmaf(kv[2], xv[q * 4 + 2], part[r]);
                    part[r] = fmaf(kv[3], xv[q * 4 + 3], part[r]);
                }
            }
            // Full butterfly over cl-bits: every lane ends with all 16 totals.
            #pragma unroll
            for (int off = 1; off < 16; off <<= 1) {
                #pragma unroll
                for (int r = 0; r < 16; ++r)
                    part[r] += __shfl_xor(part[r], off, 64);
            }
            // Lane (rl,cl) stores row R0+rl*16+cl -> base + R0 + t (coalesced).
            float myv = part[0];
            #pragma unroll
            for (int r = 1; r < 16; ++r) myv = (cl == r) ? part[r] : myv;
            st_agent(yrp + ((size_t)sC * 16 + bC) * N + R0 + t, sgn_cur * myv);
        }

        // ---- AF stage: AF = AT/(1+sum_c yrp[sC][c][R0+t]) ----
        {
            const float sum = poll_sum16(yrp + (size_t)sC * 16 * N + R0 + t, sgn_cur);
            xsh2[t] = at_val / (1.0f + sum);
        }
        sync_lds();

        // ---- colPhase: y_col partial for this tile ----
        {
            float av[16];
            #pragma unroll
            for (int r = 0; r < 16; ++r) av[r] = xsh2[rl * 16 + r];
            float part[16];
            #pragma unroll
            for (int c = 0; c < 16; ++c) part[c] = 0.0f;
            #pragma unroll
            for (int r = 0; r < RREG; ++r) {
                const float a = av[r];
                #pragma unroll
                for (int c = 0; c < 16; ++c)
                    part[c] = fmaf(k[r * 16 + c], a, part[c]);
            }
            #pragma unroll
            for (int r = RREG; r < 16; ++r) {
                const float a = av[r];
                #pragma unroll
                for (int q = 0; q < 4; ++q) {
                    f32x4 kv = kl4[(((r - RREG) * 4 + q) * 4 + w) * 64 + l];
                    part[q * 4 + 0] = fmaf(kv[0], a, part[q * 4 + 0]);
                    part[q * 4 + 1] = fmaf(kv[1], a, part[q * 4 + 1]);
                    part[q * 4 + 2] = fmaf(kv[2], a, part[q * 4 + 2]);
                    part[q * 4 + 3] = fmaf(kv[3], a, part[q * 4 + 3]);
                }
            }
            #pragma unroll
            for (int c = 0; c < 16; ++c) {
                part[c] += __shfl_xor(part[c], 16, 64);
                part[c] += __shfl_xor(part[c], 32, 64);
            }
            if ((t & 63) < 16) {          // one lane per cl per wave
                #pragma unroll
                for (int c = 0; c < 16; ++c)
                    red[w * 256 + cl * 16 + c] = part[c];
            }
            sync_lds();
            const float s4 = red[t] + red[256 + t] + red[512 + t] + red[768 + t];
            st_agent(ycp + ((size_t)sC * 16 + bR) * N + C0 + t, sgn_cur * s4);
        }
    }

    // ---- Epilogue: C = K * AF[:,None] * BF[None,:] ----
    // AF(20) still in xsh2. BF_final from y_col(20): slot 20%3=2, sign +.
    sync_lds();   // all waves past their red reads before red is reused
    {
        const float sum = poll_sum16(ycp + (size_t)2 * 16 * N + C0 + t, 1.0f);
        red[t] = bt_val / (1.0f + sum);
    }
    sync_lds();

    float af[16], bf[16];
    #pragma unroll
    for (int r = 0; r < 16; ++r) af[r] = xsh2[rl * 16 + r];
    #pragma unroll
    for (int c = 0; c < 16; ++c) bf[c] = red[cl * 16 + c];

    #pragma unroll
    for (int r = 0; r < 16; ++r) {
        float4* dst = (float4*)(C + (size_t)(row0 + r) * N + col0);
        const float a = af[r];
        #pragma unroll
        for (int q = 0; q < 4; ++q) {
            f32x4 kv;
            if (r < RREG) {
                kv[0] = k[r * 16 + q * 4 + 0];
                kv[1] = k[r * 16 + q * 4 + 1];
                kv[2] = k[r * 16 + q * 4 + 2];
                kv[3] = k[r * 16 + q * 4 + 3];
            } else {
                kv = kl4[(((r - RREG) * 4 + q) * 4 + w) * 64 + l];
            }
            float4 o;
            o.x = kv[0] * a * bf[q * 4 + 0];
            o.y = kv[1] * a * bf[q * 4 + 1];
            o.z = kv[2] * a * bf[q * 4 + 2];
            o.w = kv[3] * a * bf[q * 4 + 3];
            dst[q] = o;
        }
    }
}

extern "C" void kernel_launch(void* const* d_in, const int* in_sizes, int n_in,
                              void* d_out, int out_size, void* d_ws, size_t ws_size,
                              hipStream_t stream) {
    const float* AT = (const float*)d_in[0];
    const float* BT = (const float*)d_in[1];
    const float* P  = (const float*)d_in[2];
    float*       C  = (float*)d_out;
    float*       ws = (float*)d_ws;

    // Zero the 2 x 3 x 16 x 4096 partial region (1.5 MiB). Zero (like the
    // 0xAA poison = -3.03e-13) is magnitude-invalid for both parities, so
    // any pre-state is safe; memset is cheap insurance.
    hipMemsetAsync(d_ws, 0, 2 * 3 * 16 * (size_t)N * sizeof(float), stream);

    competitive_persistent<<<dim3(NBLK), dim3(256), 0, stream>>>(AT, BT, P, C, ws);
}